// Round 1
// baseline (588.753 us; speedup 1.0000x reference)
//
#include <hip/hip_runtime.h>

#define N_NODES 50000
#define N_EDGES 800000
#define IN_CH 64
#define HID 128

// ---------------- CSR build ----------------

__global__ void count_edges(const int* __restrict__ dst, int* __restrict__ counts, int e) {
    int i = blockIdx.x * blockDim.x + threadIdx.x;
    if (i < e) atomicAdd(&counts[dst[i]], 1);
}

__global__ void scan_counts(const int* __restrict__ counts, int* __restrict__ row_ptr, int n) {
    __shared__ int sdata[1024];
    __shared__ int s_carry;
    if (threadIdx.x == 0) { s_carry = 0; row_ptr[0] = 0; }
    __syncthreads();
    for (int base = 0; base < n; base += 1024) {
        int i = base + (int)threadIdx.x;
        int v = (i < n) ? counts[i] : 0;
        sdata[threadIdx.x] = v;
        __syncthreads();
        for (int off = 1; off < 1024; off <<= 1) {
            int t = (threadIdx.x >= (unsigned)off) ? sdata[threadIdx.x - off] : 0;
            __syncthreads();
            sdata[threadIdx.x] += t;
            __syncthreads();
        }
        if (i < n) row_ptr[i + 1] = s_carry + sdata[threadIdx.x];
        int total = sdata[1023];
        __syncthreads();
        if (threadIdx.x == 0) s_carry += total;
        __syncthreads();
    }
}

__global__ void fill_csr(const int* __restrict__ src, const int* __restrict__ dst,
                         const float* __restrict__ w, const int* __restrict__ row_ptr,
                         int* __restrict__ cursor, int* __restrict__ csr_src,
                         float* __restrict__ csr_w, int e) {
    int i = blockIdx.x * blockDim.x + threadIdx.x;
    if (i >= e) return;
    int d = dst[i];
    int p = row_ptr[d] + atomicAdd(&cursor[d], 1);
    csr_src[p] = src[i];
    csr_w[p] = w[i];
}

// ---------------- Aggregation: one wave per node ----------------

template <int CH>
__global__ void aggregate(const float* __restrict__ h, const int* __restrict__ row_ptr,
                          const int* __restrict__ csr_src, const float* __restrict__ csr_w,
                          float* __restrict__ agg, int n) {
    int lane = threadIdx.x & 63;
    int node = (int)((blockIdx.x * blockDim.x + threadIdx.x) >> 6);
    if (node >= n) return;
    int beg = row_ptr[node], end = row_ptr[node + 1];
    float denom = fmaxf((float)(end - beg), 1.0f);
    float inv = 1.0f / denom;
    if (CH == 64) {
        float acc = 0.0f;
        for (int e = beg; e < end; ++e) {
            acc += csr_w[e] * h[csr_src[e] * 64 + lane];
        }
        agg[node * 64 + lane] = acc * inv;
    } else {
        float ax = 0.0f, ay = 0.0f;
        const float2* h2 = (const float2*)h;
        for (int e = beg; e < end; ++e) {
            float wv = csr_w[e];
            float2 hv = h2[csr_src[e] * 64 + lane];
            ax += wv * hv.x;
            ay += wv * hv.y;
        }
        float2 out;
        out.x = ax * inv;
        out.y = ay * inv;
        ((float2*)agg)[node * 64 + lane] = out;
    }
}

// ---------------- Fused dual GEMM: Y = act(A@Wa^T + B@Wb^T + bias) ----------------
// A: n x K, Wa: 128 x K, B: n x K (nullptr => skip), Wb: 128 x K, Y: n x 128
// Block tile: 64 nodes x 128 outputs, 256 threads, thread tile 4 nodes x 8 outputs.

template <int K, bool RELU>
__global__ __launch_bounds__(256) void gemm_dual(
    const float* __restrict__ A, const float* __restrict__ Wa,
    const float* __restrict__ B, const float* __restrict__ Wb,
    const float* __restrict__ bias, float* __restrict__ Y, int n) {
    __shared__ __align__(16) float At[16][68];   // [k][node], padded
    __shared__ __align__(16) float Wt[16][132];  // [k][j], padded
    const int tid = (int)threadIdx.x;
    const int jg = tid & 15;   // output group: j = jg*8 .. jg*8+7
    const int ng = tid >> 4;   // node group: local node = ng*4 .. ng*4+3
    const int n0 = (int)blockIdx.x * 64;

    float acc[4][8];
#pragma unroll
    for (int i = 0; i < 4; ++i)
#pragma unroll
        for (int j = 0; j < 8; ++j) acc[i][j] = 0.0f;

    for (int m = 0; m < 2; ++m) {
        const float* In = m ? B : A;
        const float* W = m ? Wb : Wa;
        if (In == nullptr) continue;
        for (int k0 = 0; k0 < K; k0 += 16) {
            // stage A-tile (transpose to [k][node])
            {
                int nn = tid >> 2;      // 0..63
                int kq = tid & 3;       // 0..3
                float4 v = make_float4(0.f, 0.f, 0.f, 0.f);
                int node = n0 + nn;
                if (node < n) v = *(const float4*)&In[(size_t)node * K + k0 + kq * 4];
                At[kq * 4 + 0][nn] = v.x;
                At[kq * 4 + 1][nn] = v.y;
                At[kq * 4 + 2][nn] = v.z;
                At[kq * 4 + 3][nn] = v.w;
            }
            // stage W-tile (transpose to [k][j])
            {
                int j = tid >> 1;       // 0..127
                int kq2 = tid & 1;      // 0..1
                const float* wp = &W[(size_t)j * K + k0 + kq2 * 8];
                float4 w0 = *(const float4*)&wp[0];
                float4 w1 = *(const float4*)&wp[4];
                Wt[kq2 * 8 + 0][j] = w0.x;
                Wt[kq2 * 8 + 1][j] = w0.y;
                Wt[kq2 * 8 + 2][j] = w0.z;
                Wt[kq2 * 8 + 3][j] = w0.w;
                Wt[kq2 * 8 + 4][j] = w1.x;
                Wt[kq2 * 8 + 5][j] = w1.y;
                Wt[kq2 * 8 + 6][j] = w1.z;
                Wt[kq2 * 8 + 7][j] = w1.w;
            }
            __syncthreads();
#pragma unroll
            for (int kk = 0; kk < 16; ++kk) {
                float4 a = *(const float4*)&At[kk][ng * 4];
                float4 w0 = *(const float4*)&Wt[kk][jg * 8];
                float4 w1 = *(const float4*)&Wt[kk][jg * 8 + 4];
                float av[4] = {a.x, a.y, a.z, a.w};
                float wv[8] = {w0.x, w0.y, w0.z, w0.w, w1.x, w1.y, w1.z, w1.w};
#pragma unroll
                for (int i = 0; i < 4; ++i)
#pragma unroll
                    for (int j = 0; j < 8; ++j) acc[i][j] += av[i] * wv[j];
            }
            __syncthreads();
        }
    }

    // epilogue
    float bv[8];
#pragma unroll
    for (int j = 0; j < 8; ++j) bv[j] = bias[jg * 8 + j];
#pragma unroll
    for (int i = 0; i < 4; ++i) {
        int node = n0 + ng * 4 + i;
        if (node >= n) continue;
        float4 o0, o1;
        o0.x = acc[i][0] + bv[0];
        o0.y = acc[i][1] + bv[1];
        o0.z = acc[i][2] + bv[2];
        o0.w = acc[i][3] + bv[3];
        o1.x = acc[i][4] + bv[4];
        o1.y = acc[i][5] + bv[5];
        o1.z = acc[i][6] + bv[6];
        o1.w = acc[i][7] + bv[7];
        if (RELU) {
            o0.x = fmaxf(o0.x, 0.f); o0.y = fmaxf(o0.y, 0.f);
            o0.z = fmaxf(o0.z, 0.f); o0.w = fmaxf(o0.w, 0.f);
            o1.x = fmaxf(o1.x, 0.f); o1.y = fmaxf(o1.y, 0.f);
            o1.z = fmaxf(o1.z, 0.f); o1.w = fmaxf(o1.w, 0.f);
        }
        float* yp = &Y[(size_t)node * 128 + jg * 8];
        *(float4*)&yp[0] = o0;
        *(float4*)&yp[4] = o1;
    }
}

// ---------------- Prediction head: out[n] = h[n,:] . Wprd + b ----------------

__global__ void predict(const float* __restrict__ h, const float* __restrict__ Wp,
                        const float* __restrict__ bp, float* __restrict__ out, int n) {
    int lane = threadIdx.x & 63;
    int node = (int)((blockIdx.x * blockDim.x + threadIdx.x) >> 6);
    if (node >= n) return;
    float2 hv = ((const float2*)h)[node * 64 + lane];
    float2 wv = ((const float2*)Wp)[lane];
    float v = hv.x * wv.x + hv.y * wv.y;
#pragma unroll
    for (int off = 32; off > 0; off >>= 1) v += __shfl_down(v, off);
    if (lane == 0) out[node] = v + bp[0];
}

// ---------------- Launch ----------------

extern "C" void kernel_launch(void* const* d_in, const int* in_sizes, int n_in,
                              void* d_out, int out_size, void* d_ws, size_t ws_size,
                              hipStream_t stream) {
    const float* x = (const float*)d_in[0];
    const int* edge_index = (const int*)d_in[1];
    const float* edge_w = (const float*)d_in[2];
    const float* W_rel0 = (const float*)d_in[3];
    const float* b_rel0 = (const float*)d_in[4];
    const float* W_root0 = (const float*)d_in[5];
    const float* W_ro0 = (const float*)d_in[6];
    const float* b_ro0 = (const float*)d_in[7];
    const float* W_rel1 = (const float*)d_in[8];
    const float* b_rel1 = (const float*)d_in[9];
    const float* W_root1 = (const float*)d_in[10];
    const float* W_ro1 = (const float*)d_in[11];
    const float* b_ro1 = (const float*)d_in[12];
    const float* W_prd = (const float*)d_in[13];
    const float* b_prd = (const float*)d_in[14];
    float* out = (float*)d_out;

    const int* e_src = edge_index;
    const int* e_dst = edge_index + N_EDGES;

    // workspace carve-up (all 256B-aligned)
    char* ws = (char*)d_ws;
    size_t off = 0;
    auto alloc = [&](size_t bytes) {
        char* p = ws + off;
        off += (bytes + 255) & ~(size_t)255;
        return p;
    };
    int* counts = (int*)alloc(N_NODES * 4);
    int* cursor = (int*)alloc(N_NODES * 4);
    int* row_ptr = (int*)alloc((N_NODES + 1) * 4);
    int* csr_src = (int*)alloc(N_EDGES * 4);
    float* csr_w = (float*)alloc(N_EDGES * 4);
    float* AGG = (float*)alloc((size_t)N_NODES * 128 * 4);
    float* B1 = (float*)alloc((size_t)N_NODES * 128 * 4);
    float* B2 = (float*)alloc((size_t)N_NODES * 128 * 4);

    hipMemsetAsync(counts, 0, N_NODES * 4, stream);
    hipMemsetAsync(cursor, 0, N_NODES * 4, stream);

    const int EB = (N_EDGES + 255) / 256;
    count_edges<<<EB, 256, 0, stream>>>(e_dst, counts, N_EDGES);
    scan_counts<<<1, 1024, 0, stream>>>(counts, row_ptr, N_NODES);
    fill_csr<<<EB, 256, 0, stream>>>(e_src, e_dst, edge_w, row_ptr, cursor, csr_src, csr_w, N_EDGES);

    const int AGGB = (N_NODES * 64 + 255) / 256;   // wave per node
    const int GB = (N_NODES + 63) / 64;            // gemm blocks

    // layer 0: agg0 = segsum(w * x[src]) / denom  (64 ch)
    aggregate<64><<<AGGB, 256, 0, stream>>>(x, row_ptr, csr_src, csr_w, AGG, N_NODES);
    // h1 = relu(agg0 @ W_rel0^T + x @ W_root0^T + b_rel0)
    gemm_dual<64, true><<<GB, 256, 0, stream>>>(AGG, W_rel0, x, W_root0, b_rel0, B1, N_NODES);
    // h2 = relu(h1 @ W_ro0^T + b_ro0)
    gemm_dual<128, true><<<GB, 256, 0, stream>>>(B1, W_ro0, nullptr, nullptr, b_ro0, B2, N_NODES);
    // layer 1: agg1 = segsum(w * h2[src]) / denom  (128 ch)
    aggregate<128><<<AGGB, 256, 0, stream>>>(B2, row_ptr, csr_src, csr_w, AGG, N_NODES);
    // h3 = relu(agg1 @ W_rel1^T + h2 @ W_root1^T + b_rel1)
    gemm_dual<128, true><<<GB, 256, 0, stream>>>(AGG, W_rel1, B2, W_root1, b_rel1, B1, N_NODES);
    // h4 = relu(h3 @ W_ro1^T + b_ro1)
    gemm_dual<128, true><<<GB, 256, 0, stream>>>(B1, W_ro1, nullptr, nullptr, b_ro1, B2, N_NODES);
    // out = h4 @ W_prd^T + b_prd
    predict<<<AGGB, 256, 0, stream>>>(B2, W_prd, b_prd, out, N_NODES);
}

// Round 2
// 490.588 us; speedup vs baseline: 1.2001x; 1.2001x over previous
//
#include <hip/hip_runtime.h>

#define N_NODES 50000
#define N_EDGES 800000
#define IN_CH 64
#define HID 128

// ---------------- CSR build ----------------

__global__ void count_edges(const int* __restrict__ dst, int* __restrict__ counts, int e) {
    int i = blockIdx.x * blockDim.x + threadIdx.x;
    if (i < e) atomicAdd(&counts[dst[i]], 1);
}

// Hierarchical scan, stage 1: 256 threads x 4 elems = 1024 per block.
// Writes block-local inclusive scan + per-block totals.
__global__ __launch_bounds__(256) void scan_block(const int* __restrict__ counts,
                                                  int* __restrict__ partial,
                                                  int* __restrict__ block_sums, int n) {
    __shared__ int wsum[4];
    int base = (int)blockIdx.x * 1024 + (int)threadIdx.x * 4;
    int4 v = make_int4(0, 0, 0, 0);
    if (base + 3 < n) {
        v = *(const int4*)&counts[base];
    } else {
        if (base + 0 < n) v.x = counts[base + 0];
        if (base + 1 < n) v.y = counts[base + 1];
        if (base + 2 < n) v.z = counts[base + 2];
        if (base + 3 < n) v.w = counts[base + 3];
    }
    v.y += v.x; v.z += v.y; v.w += v.z;
    int tot = v.w;
    int lane = (int)threadIdx.x & 63;
    int wid = (int)threadIdx.x >> 6;
    int s = tot;
#pragma unroll
    for (int off = 1; off < 64; off <<= 1) {
        int t = __shfl_up(s, off);
        if (lane >= off) s += t;
    }
    if (lane == 63) wsum[wid] = s;
    __syncthreads();
    int woff = 0;
#pragma unroll
    for (int w = 0; w < 4; ++w)
        if (w < wid) woff += wsum[w];
    int excl = woff + s - tot;  // exclusive prefix for this thread within block
    v.x += excl; v.y += excl; v.z += excl; v.w += excl;
    if (base + 3 < n) {
        *(int4*)&partial[base] = v;
    } else {
        if (base + 0 < n) partial[base + 0] = v.x;
        if (base + 1 < n) partial[base + 1] = v.y;
        if (base + 2 < n) partial[base + 2] = v.z;
        if (base + 3 < n) partial[base + 3] = v.w;
    }
    if (threadIdx.x == 255) block_sums[blockIdx.x] = woff + s;
}

// Stage 2: each block computes its global offset by wave-reducing preceding
// block totals (nblocks <= 64), then writes row_ptr[i+1] = partial[i] + off.
__global__ __launch_bounds__(256) void finalize_rowptr(const int* __restrict__ partial,
                                                       const int* __restrict__ block_sums,
                                                       int* __restrict__ row_ptr,
                                                       int n, int nblocks) {
    __shared__ int s_off;
    if (threadIdx.x < 64) {
        int lane = (int)threadIdx.x;
        int v = (lane < (int)blockIdx.x && lane < nblocks) ? block_sums[lane] : 0;
#pragma unroll
        for (int off = 32; off > 0; off >>= 1) v += __shfl_down(v, off);
        if (lane == 0) s_off = v;
    }
    __syncthreads();
    int off = s_off;
    int base = (int)blockIdx.x * 1024 + (int)threadIdx.x * 4;
#pragma unroll
    for (int q = 0; q < 4; ++q) {
        int i = base + q;
        if (i < n) row_ptr[i + 1] = partial[i] + off;
    }
    if (blockIdx.x == 0 && threadIdx.x == 0) row_ptr[0] = 0;
}

__global__ void fill_csr(const int* __restrict__ src, const int* __restrict__ dst,
                         const float* __restrict__ w, const int* __restrict__ row_ptr,
                         int* __restrict__ cursor, int* __restrict__ csr_src,
                         float* __restrict__ csr_w, int e) {
    int i = blockIdx.x * blockDim.x + threadIdx.x;
    if (i >= e) return;
    int d = dst[i];
    int p = row_ptr[d] + atomicAdd(&cursor[d], 1);
    csr_src[p] = src[i];
    csr_w[p] = w[i];
}

// ---------------- Aggregation: one wave per node ----------------

template <int CH>
__global__ void aggregate(const float* __restrict__ h, const int* __restrict__ row_ptr,
                          const int* __restrict__ csr_src, const float* __restrict__ csr_w,
                          float* __restrict__ agg, int n) {
    int lane = threadIdx.x & 63;
    int node = (int)((blockIdx.x * blockDim.x + threadIdx.x) >> 6);
    if (node >= n) return;
    int beg = row_ptr[node], end = row_ptr[node + 1];
    float denom = fmaxf((float)(end - beg), 1.0f);
    float inv = 1.0f / denom;
    if (CH == 64) {
        float acc = 0.0f;
        for (int e = beg; e < end; ++e) {
            acc += csr_w[e] * h[csr_src[e] * 64 + lane];
        }
        agg[node * 64 + lane] = acc * inv;
    } else {
        float ax = 0.0f, ay = 0.0f;
        const float2* h2 = (const float2*)h;
        for (int e = beg; e < end; ++e) {
            float wv = csr_w[e];
            float2 hv = h2[csr_src[e] * 64 + lane];
            ax += wv * hv.x;
            ay += wv * hv.y;
        }
        float2 out;
        out.x = ax * inv;
        out.y = ay * inv;
        ((float2*)agg)[node * 64 + lane] = out;
    }
}

// ---------------- Fused dual GEMM: Y = act(A@Wa^T + B@Wb^T + bias) ----------------

template <int K, bool RELU>
__global__ __launch_bounds__(256) void gemm_dual(
    const float* __restrict__ A, const float* __restrict__ Wa,
    const float* __restrict__ B, const float* __restrict__ Wb,
    const float* __restrict__ bias, float* __restrict__ Y, int n) {
    __shared__ __align__(16) float At[16][68];   // [k][node], padded
    __shared__ __align__(16) float Wt[16][132];  // [k][j], padded
    const int tid = (int)threadIdx.x;
    const int jg = tid & 15;   // output group: j = jg*8 .. jg*8+7
    const int ng = tid >> 4;   // node group: local node = ng*4 .. ng*4+3
    const int n0 = (int)blockIdx.x * 64;

    float acc[4][8];
#pragma unroll
    for (int i = 0; i < 4; ++i)
#pragma unroll
        for (int j = 0; j < 8; ++j) acc[i][j] = 0.0f;

    for (int m = 0; m < 2; ++m) {
        const float* In = m ? B : A;
        const float* W = m ? Wb : Wa;
        if (In == nullptr) continue;
        for (int k0 = 0; k0 < K; k0 += 16) {
            {
                int nn = tid >> 2;
                int kq = tid & 3;
                float4 v = make_float4(0.f, 0.f, 0.f, 0.f);
                int node = n0 + nn;
                if (node < n) v = *(const float4*)&In[(size_t)node * K + k0 + kq * 4];
                At[kq * 4 + 0][nn] = v.x;
                At[kq * 4 + 1][nn] = v.y;
                At[kq * 4 + 2][nn] = v.z;
                At[kq * 4 + 3][nn] = v.w;
            }
            {
                int j = tid >> 1;
                int kq2 = tid & 1;
                const float* wp = &W[(size_t)j * K + k0 + kq2 * 8];
                float4 w0 = *(const float4*)&wp[0];
                float4 w1 = *(const float4*)&wp[4];
                Wt[kq2 * 8 + 0][j] = w0.x;
                Wt[kq2 * 8 + 1][j] = w0.y;
                Wt[kq2 * 8 + 2][j] = w0.z;
                Wt[kq2 * 8 + 3][j] = w0.w;
                Wt[kq2 * 8 + 4][j] = w1.x;
                Wt[kq2 * 8 + 5][j] = w1.y;
                Wt[kq2 * 8 + 6][j] = w1.z;
                Wt[kq2 * 8 + 7][j] = w1.w;
            }
            __syncthreads();
#pragma unroll
            for (int kk = 0; kk < 16; ++kk) {
                float4 a = *(const float4*)&At[kk][ng * 4];
                float4 w0 = *(const float4*)&Wt[kk][jg * 8];
                float4 w1 = *(const float4*)&Wt[kk][jg * 8 + 4];
                float av[4] = {a.x, a.y, a.z, a.w};
                float wv[8] = {w0.x, w0.y, w0.z, w0.w, w1.x, w1.y, w1.z, w1.w};
#pragma unroll
                for (int i = 0; i < 4; ++i)
#pragma unroll
                    for (int j = 0; j < 8; ++j) acc[i][j] += av[i] * wv[j];
            }
            __syncthreads();
        }
    }

    float bv[8];
#pragma unroll
    for (int j = 0; j < 8; ++j) bv[j] = bias[jg * 8 + j];
#pragma unroll
    for (int i = 0; i < 4; ++i) {
        int node = n0 + ng * 4 + i;
        if (node >= n) continue;
        float4 o0, o1;
        o0.x = acc[i][0] + bv[0];
        o0.y = acc[i][1] + bv[1];
        o0.z = acc[i][2] + bv[2];
        o0.w = acc[i][3] + bv[3];
        o1.x = acc[i][4] + bv[4];
        o1.y = acc[i][5] + bv[5];
        o1.z = acc[i][6] + bv[6];
        o1.w = acc[i][7] + bv[7];
        if (RELU) {
            o0.x = fmaxf(o0.x, 0.f); o0.y = fmaxf(o0.y, 0.f);
            o0.z = fmaxf(o0.z, 0.f); o0.w = fmaxf(o0.w, 0.f);
            o1.x = fmaxf(o1.x, 0.f); o1.y = fmaxf(o1.y, 0.f);
            o1.z = fmaxf(o1.z, 0.f); o1.w = fmaxf(o1.w, 0.f);
        }
        float* yp = &Y[(size_t)node * 128 + jg * 8];
        *(float4*)&yp[0] = o0;
        *(float4*)&yp[4] = o1;
    }
}

// ---------------- Prediction head ----------------

__global__ void predict(const float* __restrict__ h, const float* __restrict__ Wp,
                        const float* __restrict__ bp, float* __restrict__ out, int n) {
    int lane = threadIdx.x & 63;
    int node = (int)((blockIdx.x * blockDim.x + threadIdx.x) >> 6);
    if (node >= n) return;
    float2 hv = ((const float2*)h)[node * 64 + lane];
    float2 wv = ((const float2*)Wp)[lane];
    float v = hv.x * wv.x + hv.y * wv.y;
#pragma unroll
    for (int off = 32; off > 0; off >>= 1) v += __shfl_down(v, off);
    if (lane == 0) out[node] = v + bp[0];
}

// ---------------- Launch ----------------

extern "C" void kernel_launch(void* const* d_in, const int* in_sizes, int n_in,
                              void* d_out, int out_size, void* d_ws, size_t ws_size,
                              hipStream_t stream) {
    const float* x = (const float*)d_in[0];
    const int* edge_index = (const int*)d_in[1];
    const float* edge_w = (const float*)d_in[2];
    const float* W_rel0 = (const float*)d_in[3];
    const float* b_rel0 = (const float*)d_in[4];
    const float* W_root0 = (const float*)d_in[5];
    const float* W_ro0 = (const float*)d_in[6];
    const float* b_ro0 = (const float*)d_in[7];
    const float* W_rel1 = (const float*)d_in[8];
    const float* b_rel1 = (const float*)d_in[9];
    const float* W_root1 = (const float*)d_in[10];
    const float* W_ro1 = (const float*)d_in[11];
    const float* b_ro1 = (const float*)d_in[12];
    const float* W_prd = (const float*)d_in[13];
    const float* b_prd = (const float*)d_in[14];
    float* out = (float*)d_out;

    const int* e_src = edge_index;
    const int* e_dst = edge_index + N_EDGES;

    char* ws = (char*)d_ws;
    size_t off = 0;
    auto alloc = [&](size_t bytes) {
        char* p = ws + off;
        off += (bytes + 255) & ~(size_t)255;
        return p;
    };
    int* counts = (int*)alloc(N_NODES * 4);
    int* cursor = (int*)alloc(N_NODES * 4);
    int* row_ptr = (int*)alloc((N_NODES + 1) * 4);
    int* partial = (int*)alloc(N_NODES * 4);
    int* block_sums = (int*)alloc(64 * 4);
    int* csr_src = (int*)alloc(N_EDGES * 4);
    float* csr_w = (float*)alloc(N_EDGES * 4);
    float* AGG = (float*)alloc((size_t)N_NODES * 128 * 4);
    float* B1 = (float*)alloc((size_t)N_NODES * 128 * 4);
    float* B2 = (float*)alloc((size_t)N_NODES * 128 * 4);

    hipMemsetAsync(counts, 0, N_NODES * 4, stream);
    hipMemsetAsync(cursor, 0, N_NODES * 4, stream);

    const int EB = (N_EDGES + 255) / 256;
    const int SB = (N_NODES + 1023) / 1024;  // 49 scan blocks (<= 64 required)
    count_edges<<<EB, 256, 0, stream>>>(e_dst, counts, N_EDGES);
    scan_block<<<SB, 256, 0, stream>>>(counts, partial, block_sums, N_NODES);
    finalize_rowptr<<<SB, 256, 0, stream>>>(partial, block_sums, row_ptr, N_NODES, SB);
    fill_csr<<<EB, 256, 0, stream>>>(e_src, e_dst, edge_w, row_ptr, cursor, csr_src, csr_w, N_EDGES);

    const int AGGB = (N_NODES * 64 + 255) / 256;
    const int GB = (N_NODES + 63) / 64;

    aggregate<64><<<AGGB, 256, 0, stream>>>(x, row_ptr, csr_src, csr_w, AGG, N_NODES);
    gemm_dual<64, true><<<GB, 256, 0, stream>>>(AGG, W_rel0, x, W_root0, b_rel0, B1, N_NODES);
    gemm_dual<128, true><<<GB, 256, 0, stream>>>(B1, W_ro0, nullptr, nullptr, b_ro0, B2, N_NODES);
    aggregate<128><<<AGGB, 256, 0, stream>>>(B2, row_ptr, csr_src, csr_w, AGG, N_NODES);
    gemm_dual<128, true><<<GB, 256, 0, stream>>>(AGG, W_rel1, B2, W_root1, b_rel1, B1, N_NODES);
    gemm_dual<128, true><<<GB, 256, 0, stream>>>(B1, W_ro1, nullptr, nullptr, b_ro1, B2, N_NODES);
    predict<<<AGGB, 256, 0, stream>>>(B2, W_prd, b_prd, out, N_NODES);
}

// Round 3
// 423.260 us; speedup vs baseline: 1.3910x; 1.1591x over previous
//
#include <hip/hip_runtime.h>

#define N_NODES 50000
#define N_EDGES 800000
#define IN_CH 64
#define HID 128

// ---------------- CSR build ----------------

__global__ void count_edges(const int* __restrict__ dst, int* __restrict__ counts, int e) {
    int i = blockIdx.x * blockDim.x + threadIdx.x;
    if (i < e) atomicAdd(&counts[dst[i]], 1);
}

// Hierarchical scan, stage 1: 256 threads x 4 elems = 1024 per block.
__global__ __launch_bounds__(256) void scan_block(const int* __restrict__ counts,
                                                  int* __restrict__ partial,
                                                  int* __restrict__ block_sums, int n) {
    __shared__ int wsum[4];
    int base = (int)blockIdx.x * 1024 + (int)threadIdx.x * 4;
    int4 v = make_int4(0, 0, 0, 0);
    if (base + 3 < n) {
        v = *(const int4*)&counts[base];
    } else {
        if (base + 0 < n) v.x = counts[base + 0];
        if (base + 1 < n) v.y = counts[base + 1];
        if (base + 2 < n) v.z = counts[base + 2];
        if (base + 3 < n) v.w = counts[base + 3];
    }
    v.y += v.x; v.z += v.y; v.w += v.z;
    int tot = v.w;
    int lane = (int)threadIdx.x & 63;
    int wid = (int)threadIdx.x >> 6;
    int s = tot;
#pragma unroll
    for (int off = 1; off < 64; off <<= 1) {
        int t = __shfl_up(s, off);
        if (lane >= off) s += t;
    }
    if (lane == 63) wsum[wid] = s;
    __syncthreads();
    int woff = 0;
#pragma unroll
    for (int w = 0; w < 4; ++w)
        if (w < wid) woff += wsum[w];
    int excl = woff + s - tot;
    v.x += excl; v.y += excl; v.z += excl; v.w += excl;
    if (base + 3 < n) {
        *(int4*)&partial[base] = v;
    } else {
        if (base + 0 < n) partial[base + 0] = v.x;
        if (base + 1 < n) partial[base + 1] = v.y;
        if (base + 2 < n) partial[base + 2] = v.z;
        if (base + 3 < n) partial[base + 3] = v.w;
    }
    if (threadIdx.x == 255) block_sums[blockIdx.x] = woff + s;
}

__global__ __launch_bounds__(256) void finalize_rowptr(const int* __restrict__ partial,
                                                       const int* __restrict__ block_sums,
                                                       int* __restrict__ row_ptr,
                                                       int n, int nblocks) {
    __shared__ int s_off;
    if (threadIdx.x < 64) {
        int lane = (int)threadIdx.x;
        int v = (lane < (int)blockIdx.x && lane < nblocks) ? block_sums[lane] : 0;
#pragma unroll
        for (int off = 32; off > 0; off >>= 1) v += __shfl_down(v, off);
        if (lane == 0) s_off = v;
    }
    __syncthreads();
    int off = s_off;
    int base = (int)blockIdx.x * 1024 + (int)threadIdx.x * 4;
#pragma unroll
    for (int q = 0; q < 4; ++q) {
        int i = base + q;
        if (i < n) row_ptr[i + 1] = partial[i] + off;
    }
    if (blockIdx.x == 0 && threadIdx.x == 0) row_ptr[0] = 0;
}

__global__ void fill_csr(const int* __restrict__ src, const int* __restrict__ dst,
                         const float* __restrict__ w, const int* __restrict__ row_ptr,
                         int* __restrict__ cursor, int* __restrict__ csr_src,
                         float* __restrict__ csr_w, int e) {
    int i = blockIdx.x * blockDim.x + threadIdx.x;
    if (i >= e) return;
    int d = dst[i];
    int p = row_ptr[d] + atomicAdd(&cursor[d], 1);
    csr_src[p] = src[i];
    csr_w[p] = w[i];
}

// ---------------- Aggregation: one wave per node, unroll-8 gather pipeline ----

template <int CH>
__global__ void aggregate(const float* __restrict__ h, const int* __restrict__ row_ptr,
                          const int* __restrict__ csr_src, const float* __restrict__ csr_w,
                          float* __restrict__ agg, int n) {
    int lane = threadIdx.x & 63;
    int node = (int)((blockIdx.x * blockDim.x + threadIdx.x) >> 6);
    if (node >= n) return;
    node = __builtin_amdgcn_readfirstlane(node);  // wave-uniform -> scalar loads below
    int beg = row_ptr[node], end = row_ptr[node + 1];
    float denom = fmaxf((float)(end - beg), 1.0f);
    float inv = 1.0f / denom;

    if (CH == 64) {
        float acc = 0.0f;
        int e = beg;
        for (; e + 8 <= end; e += 8) {
            int s0 = csr_src[e + 0], s1 = csr_src[e + 1], s2 = csr_src[e + 2], s3 = csr_src[e + 3];
            int s4 = csr_src[e + 4], s5 = csr_src[e + 5], s6 = csr_src[e + 6], s7 = csr_src[e + 7];
            float w0 = csr_w[e + 0], w1 = csr_w[e + 1], w2 = csr_w[e + 2], w3 = csr_w[e + 3];
            float w4 = csr_w[e + 4], w5 = csr_w[e + 5], w6 = csr_w[e + 6], w7 = csr_w[e + 7];
            float v0 = h[s0 * 64 + lane];
            float v1 = h[s1 * 64 + lane];
            float v2 = h[s2 * 64 + lane];
            float v3 = h[s3 * 64 + lane];
            float v4 = h[s4 * 64 + lane];
            float v5 = h[s5 * 64 + lane];
            float v6 = h[s6 * 64 + lane];
            float v7 = h[s7 * 64 + lane];
            acc += w0 * v0 + w1 * v1 + w2 * v2 + w3 * v3 + w4 * v4 + w5 * v5 + w6 * v6 + w7 * v7;
        }
        for (; e < end; ++e) {
            acc += csr_w[e] * h[csr_src[e] * 64 + lane];
        }
        agg[node * 64 + lane] = acc * inv;
    } else {
        float ax = 0.0f, ay = 0.0f;
        const float2* h2 = (const float2*)h;
        int e = beg;
        for (; e + 8 <= end; e += 8) {
            int s0 = csr_src[e + 0], s1 = csr_src[e + 1], s2 = csr_src[e + 2], s3 = csr_src[e + 3];
            int s4 = csr_src[e + 4], s5 = csr_src[e + 5], s6 = csr_src[e + 6], s7 = csr_src[e + 7];
            float w0 = csr_w[e + 0], w1 = csr_w[e + 1], w2 = csr_w[e + 2], w3 = csr_w[e + 3];
            float w4 = csr_w[e + 4], w5 = csr_w[e + 5], w6 = csr_w[e + 6], w7 = csr_w[e + 7];
            float2 v0 = h2[s0 * 64 + lane];
            float2 v1 = h2[s1 * 64 + lane];
            float2 v2 = h2[s2 * 64 + lane];
            float2 v3 = h2[s3 * 64 + lane];
            float2 v4 = h2[s4 * 64 + lane];
            float2 v5 = h2[s5 * 64 + lane];
            float2 v6 = h2[s6 * 64 + lane];
            float2 v7 = h2[s7 * 64 + lane];
            ax += w0 * v0.x + w1 * v1.x + w2 * v2.x + w3 * v3.x
                + w4 * v4.x + w5 * v5.x + w6 * v6.x + w7 * v7.x;
            ay += w0 * v0.y + w1 * v1.y + w2 * v2.y + w3 * v3.y
                + w4 * v4.y + w5 * v5.y + w6 * v6.y + w7 * v7.y;
        }
        for (; e < end; ++e) {
            float wv = csr_w[e];
            float2 hv = h2[csr_src[e] * 64 + lane];
            ax += wv * hv.x;
            ay += wv * hv.y;
        }
        float2 o;
        o.x = ax * inv;
        o.y = ay * inv;
        ((float2*)agg)[node * 64 + lane] = o;
    }
}

// ---------------- Fused dual GEMM: Y = act(A@Wa^T + B@Wb^T + bias) ----------------

template <int K, bool RELU>
__global__ __launch_bounds__(256) void gemm_dual(
    const float* __restrict__ A, const float* __restrict__ Wa,
    const float* __restrict__ B, const float* __restrict__ Wb,
    const float* __restrict__ bias, float* __restrict__ Y, int n) {
    __shared__ __align__(16) float At[16][68];   // [k][node], padded
    __shared__ __align__(16) float Wt[16][132];  // [k][j], padded
    const int tid = (int)threadIdx.x;
    const int jg = tid & 15;
    const int ng = tid >> 4;
    const int n0 = (int)blockIdx.x * 64;

    float acc[4][8];
#pragma unroll
    for (int i = 0; i < 4; ++i)
#pragma unroll
        for (int j = 0; j < 8; ++j) acc[i][j] = 0.0f;

    for (int m = 0; m < 2; ++m) {
        const float* In = m ? B : A;
        const float* W = m ? Wb : Wa;
        if (In == nullptr) continue;
        for (int k0 = 0; k0 < K; k0 += 16) {
            {
                int nn = tid >> 2;
                int kq = tid & 3;
                float4 v = make_float4(0.f, 0.f, 0.f, 0.f);
                int node = n0 + nn;
                if (node < n) v = *(const float4*)&In[(size_t)node * K + k0 + kq * 4];
                At[kq * 4 + 0][nn] = v.x;
                At[kq * 4 + 1][nn] = v.y;
                At[kq * 4 + 2][nn] = v.z;
                At[kq * 4 + 3][nn] = v.w;
            }
            {
                int j = tid >> 1;
                int kq2 = tid & 1;
                const float* wp = &W[(size_t)j * K + k0 + kq2 * 8];
                float4 w0 = *(const float4*)&wp[0];
                float4 w1 = *(const float4*)&wp[4];
                Wt[kq2 * 8 + 0][j] = w0.x;
                Wt[kq2 * 8 + 1][j] = w0.y;
                Wt[kq2 * 8 + 2][j] = w0.z;
                Wt[kq2 * 8 + 3][j] = w0.w;
                Wt[kq2 * 8 + 4][j] = w1.x;
                Wt[kq2 * 8 + 5][j] = w1.y;
                Wt[kq2 * 8 + 6][j] = w1.z;
                Wt[kq2 * 8 + 7][j] = w1.w;
            }
            __syncthreads();
#pragma unroll
            for (int kk = 0; kk < 16; ++kk) {
                float4 a = *(const float4*)&At[kk][ng * 4];
                float4 w0 = *(const float4*)&Wt[kk][jg * 8];
                float4 w1 = *(const float4*)&Wt[kk][jg * 8 + 4];
                float av[4] = {a.x, a.y, a.z, a.w};
                float wv[8] = {w0.x, w0.y, w0.z, w0.w, w1.x, w1.y, w1.z, w1.w};
#pragma unroll
                for (int i = 0; i < 4; ++i)
#pragma unroll
                    for (int j = 0; j < 8; ++j) acc[i][j] += av[i] * wv[j];
            }
            __syncthreads();
        }
    }

    float bv[8];
#pragma unroll
    for (int j = 0; j < 8; ++j) bv[j] = bias[jg * 8 + j];
#pragma unroll
    for (int i = 0; i < 4; ++i) {
        int node = n0 + ng * 4 + i;
        if (node >= n) continue;
        float4 o0, o1;
        o0.x = acc[i][0] + bv[0];
        o0.y = acc[i][1] + bv[1];
        o0.z = acc[i][2] + bv[2];
        o0.w = acc[i][3] + bv[3];
        o1.x = acc[i][4] + bv[4];
        o1.y = acc[i][5] + bv[5];
        o1.z = acc[i][6] + bv[6];
        o1.w = acc[i][7] + bv[7];
        if (RELU) {
            o0.x = fmaxf(o0.x, 0.f); o0.y = fmaxf(o0.y, 0.f);
            o0.z = fmaxf(o0.z, 0.f); o0.w = fmaxf(o0.w, 0.f);
            o1.x = fmaxf(o1.x, 0.f); o1.y = fmaxf(o1.y, 0.f);
            o1.z = fmaxf(o1.z, 0.f); o1.w = fmaxf(o1.w, 0.f);
        }
        float* yp = &Y[(size_t)node * 128 + jg * 8];
        *(float4*)&yp[0] = o0;
        *(float4*)&yp[4] = o1;
    }
}

// ---------------- Prediction head ----------------

__global__ void predict(const float* __restrict__ h, const float* __restrict__ Wp,
                        const float* __restrict__ bp, float* __restrict__ out, int n) {
    int lane = threadIdx.x & 63;
    int node = (int)((blockIdx.x * blockDim.x + threadIdx.x) >> 6);
    if (node >= n) return;
    float2 hv = ((const float2*)h)[node * 64 + lane];
    float2 wv = ((const float2*)Wp)[lane];
    float v = hv.x * wv.x + hv.y * wv.y;
#pragma unroll
    for (int off = 32; off > 0; off >>= 1) v += __shfl_down(v, off);
    if (lane == 0) out[node] = v + bp[0];
}

// ---------------- Launch ----------------

extern "C" void kernel_launch(void* const* d_in, const int* in_sizes, int n_in,
                              void* d_out, int out_size, void* d_ws, size_t ws_size,
                              hipStream_t stream) {
    const float* x = (const float*)d_in[0];
    const int* edge_index = (const int*)d_in[1];
    const float* edge_w = (const float*)d_in[2];
    const float* W_rel0 = (const float*)d_in[3];
    const float* b_rel0 = (const float*)d_in[4];
    const float* W_root0 = (const float*)d_in[5];
    const float* W_ro0 = (const float*)d_in[6];
    const float* b_ro0 = (const float*)d_in[7];
    const float* W_rel1 = (const float*)d_in[8];
    const float* b_rel1 = (const float*)d_in[9];
    const float* W_root1 = (const float*)d_in[10];
    const float* W_ro1 = (const float*)d_in[11];
    const float* b_ro1 = (const float*)d_in[12];
    const float* W_prd = (const float*)d_in[13];
    const float* b_prd = (const float*)d_in[14];
    float* out = (float*)d_out;

    const int* e_src = edge_index;
    const int* e_dst = edge_index + N_EDGES;

    char* ws = (char*)d_ws;
    size_t off = 0;
    auto alloc = [&](size_t bytes) {
        char* p = ws + off;
        off += (bytes + 255) & ~(size_t)255;
        return p;
    };
    int* counts = (int*)alloc(N_NODES * 4);
    int* cursor = (int*)alloc(N_NODES * 4);
    int* row_ptr = (int*)alloc((N_NODES + 1) * 4);
    int* partial = (int*)alloc(N_NODES * 4);
    int* block_sums = (int*)alloc(64 * 4);
    int* csr_src = (int*)alloc(N_EDGES * 4);
    float* csr_w = (float*)alloc(N_EDGES * 4);
    float* AGG = (float*)alloc((size_t)N_NODES * 128 * 4);
    float* B1 = (float*)alloc((size_t)N_NODES * 128 * 4);
    float* B2 = (float*)alloc((size_t)N_NODES * 128 * 4);

    hipMemsetAsync(counts, 0, N_NODES * 4, stream);
    hipMemsetAsync(cursor, 0, N_NODES * 4, stream);

    const int EB = (N_EDGES + 255) / 256;
    const int SB = (N_NODES + 1023) / 1024;
    count_edges<<<EB, 256, 0, stream>>>(e_dst, counts, N_EDGES);
    scan_block<<<SB, 256, 0, stream>>>(counts, partial, block_sums, N_NODES);
    finalize_rowptr<<<SB, 256, 0, stream>>>(partial, block_sums, row_ptr, N_NODES, SB);
    fill_csr<<<EB, 256, 0, stream>>>(e_src, e_dst, edge_w, row_ptr, cursor, csr_src, csr_w, N_EDGES);

    const int AGGB = (N_NODES * 64 + 255) / 256;
    const int GB = (N_NODES + 63) / 64;

    aggregate<64><<<AGGB, 256, 0, stream>>>(x, row_ptr, csr_src, csr_w, AGG, N_NODES);
    gemm_dual<64, true><<<GB, 256, 0, stream>>>(AGG, W_rel0, x, W_root0, b_rel0, B1, N_NODES);
    gemm_dual<128, true><<<GB, 256, 0, stream>>>(B1, W_ro0, nullptr, nullptr, b_ro0, B2, N_NODES);
    aggregate<128><<<AGGB, 256, 0, stream>>>(B2, row_ptr, csr_src, csr_w, AGG, N_NODES);
    gemm_dual<128, true><<<GB, 256, 0, stream>>>(AGG, W_rel1, B2, W_root1, b_rel1, B1, N_NODES);
    gemm_dual<128, true><<<GB, 256, 0, stream>>>(B1, W_ro1, nullptr, nullptr, b_ro1, B2, N_NODES);
    predict<<<AGGB, 256, 0, stream>>>(B2, W_prd, b_prd, out, N_NODES);
}

// Round 4
// 408.526 us; speedup vs baseline: 1.4412x; 1.0361x over previous
//
#include <hip/hip_runtime.h>

#define N_NODES 50000
#define N_EDGES 800000
#define IN_CH 64
#define HID 128

// ---------------- CSR build ----------------

__global__ void count_edges(const int* __restrict__ dst, int* __restrict__ counts, int e) {
    int i = blockIdx.x * blockDim.x + threadIdx.x;
    if (i < e) atomicAdd(&counts[dst[i]], 1);
}

// Hierarchical scan, stage 1: 256 threads x 4 elems = 1024 per block.
__global__ __launch_bounds__(256) void scan_block(const int* __restrict__ counts,
                                                  int* __restrict__ partial,
                                                  int* __restrict__ block_sums, int n) {
    __shared__ int wsum[4];
    int base = (int)blockIdx.x * 1024 + (int)threadIdx.x * 4;
    int4 v = make_int4(0, 0, 0, 0);
    if (base + 3 < n) {
        v = *(const int4*)&counts[base];
    } else {
        if (base + 0 < n) v.x = counts[base + 0];
        if (base + 1 < n) v.y = counts[base + 1];
        if (base + 2 < n) v.z = counts[base + 2];
        if (base + 3 < n) v.w = counts[base + 3];
    }
    v.y += v.x; v.z += v.y; v.w += v.z;
    int tot = v.w;
    int lane = (int)threadIdx.x & 63;
    int wid = (int)threadIdx.x >> 6;
    int s = tot;
#pragma unroll
    for (int off = 1; off < 64; off <<= 1) {
        int t = __shfl_up(s, off);
        if (lane >= off) s += t;
    }
    if (lane == 63) wsum[wid] = s;
    __syncthreads();
    int woff = 0;
#pragma unroll
    for (int w = 0; w < 4; ++w)
        if (w < wid) woff += wsum[w];
    int excl = woff + s - tot;
    v.x += excl; v.y += excl; v.z += excl; v.w += excl;
    if (base + 3 < n) {
        *(int4*)&partial[base] = v;
    } else {
        if (base + 0 < n) partial[base + 0] = v.x;
        if (base + 1 < n) partial[base + 1] = v.y;
        if (base + 2 < n) partial[base + 2] = v.z;
        if (base + 3 < n) partial[base + 3] = v.w;
    }
    if (threadIdx.x == 255) block_sums[blockIdx.x] = woff + s;
}

__global__ __launch_bounds__(256) void finalize_rowptr(const int* __restrict__ partial,
                                                       const int* __restrict__ block_sums,
                                                       int* __restrict__ row_ptr,
                                                       int n, int nblocks) {
    __shared__ int s_off;
    if (threadIdx.x < 64) {
        int lane = (int)threadIdx.x;
        int v = (lane < (int)blockIdx.x && lane < nblocks) ? block_sums[lane] : 0;
#pragma unroll
        for (int off = 32; off > 0; off >>= 1) v += __shfl_down(v, off);
        if (lane == 0) s_off = v;
    }
    __syncthreads();
    int off = s_off;
    int base = (int)blockIdx.x * 1024 + (int)threadIdx.x * 4;
#pragma unroll
    for (int q = 0; q < 4; ++q) {
        int i = base + q;
        if (i < n) row_ptr[i + 1] = partial[i] + off;
    }
    if (blockIdx.x == 0 && threadIdx.x == 0) row_ptr[0] = 0;
}

// One 8B scattered store per edge: pack (src, weight) into int2.
__global__ void fill_csr(const int* __restrict__ src, const int* __restrict__ dst,
                         const float* __restrict__ w, const int* __restrict__ row_ptr,
                         int* __restrict__ cursor, int2* __restrict__ csr_pack, int e) {
    int i = blockIdx.x * blockDim.x + threadIdx.x;
    if (i >= e) return;
    int d = dst[i];
    int p = row_ptr[d] + atomicAdd(&cursor[d], 1);
    csr_pack[p] = make_int2(src[i], __float_as_int(w[i]));
}

// ---------------- Aggregation: one wave per node, unroll-8 gather pipeline ----

template <int CH>
__global__ void aggregate(const float* __restrict__ h, const int* __restrict__ row_ptr,
                          const int2* __restrict__ csr_pack,
                          float* __restrict__ agg, int n) {
    int lane = threadIdx.x & 63;
    int node = (int)((blockIdx.x * blockDim.x + threadIdx.x) >> 6);
    if (node >= n) return;
    node = __builtin_amdgcn_readfirstlane(node);  // wave-uniform -> scalar loads below
    int beg = row_ptr[node], end = row_ptr[node + 1];
    float denom = fmaxf((float)(end - beg), 1.0f);
    float inv = 1.0f / denom;

    if (CH == 64) {
        float acc = 0.0f;
        int e = beg;
        for (; e + 8 <= end; e += 8) {
            int2 p0 = csr_pack[e + 0], p1 = csr_pack[e + 1], p2 = csr_pack[e + 2], p3 = csr_pack[e + 3];
            int2 p4 = csr_pack[e + 4], p5 = csr_pack[e + 5], p6 = csr_pack[e + 6], p7 = csr_pack[e + 7];
            float v0 = h[p0.x * 64 + lane];
            float v1 = h[p1.x * 64 + lane];
            float v2 = h[p2.x * 64 + lane];
            float v3 = h[p3.x * 64 + lane];
            float v4 = h[p4.x * 64 + lane];
            float v5 = h[p5.x * 64 + lane];
            float v6 = h[p6.x * 64 + lane];
            float v7 = h[p7.x * 64 + lane];
            acc += __int_as_float(p0.y) * v0 + __int_as_float(p1.y) * v1
                 + __int_as_float(p2.y) * v2 + __int_as_float(p3.y) * v3
                 + __int_as_float(p4.y) * v4 + __int_as_float(p5.y) * v5
                 + __int_as_float(p6.y) * v6 + __int_as_float(p7.y) * v7;
        }
        for (; e < end; ++e) {
            int2 p = csr_pack[e];
            acc += __int_as_float(p.y) * h[p.x * 64 + lane];
        }
        agg[node * 64 + lane] = acc * inv;
    } else {
        float ax = 0.0f, ay = 0.0f;
        const float2* h2 = (const float2*)h;
        int e = beg;
        for (; e + 8 <= end; e += 8) {
            int2 p0 = csr_pack[e + 0], p1 = csr_pack[e + 1], p2 = csr_pack[e + 2], p3 = csr_pack[e + 3];
            int2 p4 = csr_pack[e + 4], p5 = csr_pack[e + 5], p6 = csr_pack[e + 6], p7 = csr_pack[e + 7];
            float2 v0 = h2[p0.x * 64 + lane];
            float2 v1 = h2[p1.x * 64 + lane];
            float2 v2 = h2[p2.x * 64 + lane];
            float2 v3 = h2[p3.x * 64 + lane];
            float2 v4 = h2[p4.x * 64 + lane];
            float2 v5 = h2[p5.x * 64 + lane];
            float2 v6 = h2[p6.x * 64 + lane];
            float2 v7 = h2[p7.x * 64 + lane];
            float w0 = __int_as_float(p0.y), w1 = __int_as_float(p1.y);
            float w2 = __int_as_float(p2.y), w3 = __int_as_float(p3.y);
            float w4 = __int_as_float(p4.y), w5 = __int_as_float(p5.y);
            float w6 = __int_as_float(p6.y), w7 = __int_as_float(p7.y);
            ax += w0 * v0.x + w1 * v1.x + w2 * v2.x + w3 * v3.x
                + w4 * v4.x + w5 * v5.x + w6 * v6.x + w7 * v7.x;
            ay += w0 * v0.y + w1 * v1.y + w2 * v2.y + w3 * v3.y
                + w4 * v4.y + w5 * v5.y + w6 * v6.y + w7 * v7.y;
        }
        for (; e < end; ++e) {
            int2 p = csr_pack[e];
            float wv = __int_as_float(p.y);
            float2 hv = h2[p.x * 64 + lane];
            ax += wv * hv.x;
            ay += wv * hv.y;
        }
        float2 o;
        o.x = ax * inv;
        o.y = ay * inv;
        ((float2*)agg)[node * 64 + lane] = o;
    }
}

// ---------------- Fused dual GEMM: Y = act(A@Wa^T + B@Wb^T + bias) ----------------

template <int K, bool RELU>
__global__ __launch_bounds__(256) void gemm_dual(
    const float* __restrict__ A, const float* __restrict__ Wa,
    const float* __restrict__ B, const float* __restrict__ Wb,
    const float* __restrict__ bias, float* __restrict__ Y, int n) {
    __shared__ __align__(16) float At[16][68];   // [k][node], padded
    __shared__ __align__(16) float Wt[16][132];  // [k][j], padded
    const int tid = (int)threadIdx.x;
    const int jg = tid & 15;
    const int ng = tid >> 4;
    const int n0 = (int)blockIdx.x * 64;

    float acc[4][8];
#pragma unroll
    for (int i = 0; i < 4; ++i)
#pragma unroll
        for (int j = 0; j < 8; ++j) acc[i][j] = 0.0f;

    for (int m = 0; m < 2; ++m) {
        const float* In = m ? B : A;
        const float* W = m ? Wb : Wa;
        if (In == nullptr) continue;
        for (int k0 = 0; k0 < K; k0 += 16) {
            {
                int nn = tid >> 2;
                int kq = tid & 3;
                float4 v = make_float4(0.f, 0.f, 0.f, 0.f);
                int node = n0 + nn;
                if (node < n) v = *(const float4*)&In[(size_t)node * K + k0 + kq * 4];
                At[kq * 4 + 0][nn] = v.x;
                At[kq * 4 + 1][nn] = v.y;
                At[kq * 4 + 2][nn] = v.z;
                At[kq * 4 + 3][nn] = v.w;
            }
            {
                int j = tid >> 1;
                int kq2 = tid & 1;
                const float* wp = &W[(size_t)j * K + k0 + kq2 * 8];
                float4 w0 = *(const float4*)&wp[0];
                float4 w1 = *(const float4*)&wp[4];
                Wt[kq2 * 8 + 0][j] = w0.x;
                Wt[kq2 * 8 + 1][j] = w0.y;
                Wt[kq2 * 8 + 2][j] = w0.z;
                Wt[kq2 * 8 + 3][j] = w0.w;
                Wt[kq2 * 8 + 4][j] = w1.x;
                Wt[kq2 * 8 + 5][j] = w1.y;
                Wt[kq2 * 8 + 6][j] = w1.z;
                Wt[kq2 * 8 + 7][j] = w1.w;
            }
            __syncthreads();
#pragma unroll
            for (int kk = 0; kk < 16; ++kk) {
                float4 a = *(const float4*)&At[kk][ng * 4];
                float4 w0 = *(const float4*)&Wt[kk][jg * 8];
                float4 w1 = *(const float4*)&Wt[kk][jg * 8 + 4];
                float av[4] = {a.x, a.y, a.z, a.w};
                float wv[8] = {w0.x, w0.y, w0.z, w0.w, w1.x, w1.y, w1.z, w1.w};
#pragma unroll
                for (int i = 0; i < 4; ++i)
#pragma unroll
                    for (int j = 0; j < 8; ++j) acc[i][j] += av[i] * wv[j];
            }
            __syncthreads();
        }
    }

    float bv[8];
#pragma unroll
    for (int j = 0; j < 8; ++j) bv[j] = bias[jg * 8 + j];
#pragma unroll
    for (int i = 0; i < 4; ++i) {
        int node = n0 + ng * 4 + i;
        if (node >= n) continue;
        float4 o0, o1;
        o0.x = acc[i][0] + bv[0];
        o0.y = acc[i][1] + bv[1];
        o0.z = acc[i][2] + bv[2];
        o0.w = acc[i][3] + bv[3];
        o1.x = acc[i][4] + bv[4];
        o1.y = acc[i][5] + bv[5];
        o1.z = acc[i][6] + bv[6];
        o1.w = acc[i][7] + bv[7];
        if (RELU) {
            o0.x = fmaxf(o0.x, 0.f); o0.y = fmaxf(o0.y, 0.f);
            o0.z = fmaxf(o0.z, 0.f); o0.w = fmaxf(o0.w, 0.f);
            o1.x = fmaxf(o1.x, 0.f); o1.y = fmaxf(o1.y, 0.f);
            o1.z = fmaxf(o1.z, 0.f); o1.w = fmaxf(o1.w, 0.f);
        }
        float* yp = &Y[(size_t)node * 128 + jg * 8];
        *(float4*)&yp[0] = o0;
        *(float4*)&yp[4] = o1;
    }
}

// ---------------- Prediction head ----------------

__global__ void predict(const float* __restrict__ h, const float* __restrict__ Wp,
                        const float* __restrict__ bp, float* __restrict__ out, int n) {
    int lane = threadIdx.x & 63;
    int node = (int)((blockIdx.x * blockDim.x + threadIdx.x) >> 6);
    if (node >= n) return;
    float2 hv = ((const float2*)h)[node * 64 + lane];
    float2 wv = ((const float2*)Wp)[lane];
    float v = hv.x * wv.x + hv.y * wv.y;
#pragma unroll
    for (int off = 32; off > 0; off >>= 1) v += __shfl_down(v, off);
    if (lane == 0) out[node] = v + bp[0];
}

// ---------------- Launch ----------------

extern "C" void kernel_launch(void* const* d_in, const int* in_sizes, int n_in,
                              void* d_out, int out_size, void* d_ws, size_t ws_size,
                              hipStream_t stream) {
    const float* x = (const float*)d_in[0];
    const int* edge_index = (const int*)d_in[1];
    const float* edge_w = (const float*)d_in[2];
    const float* W_rel0 = (const float*)d_in[3];
    const float* b_rel0 = (const float*)d_in[4];
    const float* W_root0 = (const float*)d_in[5];
    const float* W_ro0 = (const float*)d_in[6];
    const float* b_ro0 = (const float*)d_in[7];
    const float* W_rel1 = (const float*)d_in[8];
    const float* b_rel1 = (const float*)d_in[9];
    const float* W_root1 = (const float*)d_in[10];
    const float* W_ro1 = (const float*)d_in[11];
    const float* b_ro1 = (const float*)d_in[12];
    const float* W_prd = (const float*)d_in[13];
    const float* b_prd = (const float*)d_in[14];
    float* out = (float*)d_out;

    const int* e_src = edge_index;
    const int* e_dst = edge_index + N_EDGES;

    char* ws = (char*)d_ws;
    size_t off = 0;
    auto alloc = [&](size_t bytes) {
        char* p = ws + off;
        off += (bytes + 255) & ~(size_t)255;
        return p;
    };
    int* counts = (int*)alloc(N_NODES * 4);
    int* cursor = (int*)alloc(N_NODES * 4);
    int* row_ptr = (int*)alloc((N_NODES + 1) * 4);
    int* partial = (int*)alloc(N_NODES * 4);
    int* block_sums = (int*)alloc(64 * 4);
    int2* csr_pack = (int2*)alloc((size_t)N_EDGES * 8);
    float* AGG = (float*)alloc((size_t)N_NODES * 128 * 4);
    float* B1 = (float*)alloc((size_t)N_NODES * 128 * 4);
    float* B2 = (float*)alloc((size_t)N_NODES * 128 * 4);

    hipMemsetAsync(counts, 0, N_NODES * 4, stream);
    hipMemsetAsync(cursor, 0, N_NODES * 4, stream);

    const int EB = (N_EDGES + 255) / 256;
    const int SB = (N_NODES + 1023) / 1024;
    count_edges<<<EB, 256, 0, stream>>>(e_dst, counts, N_EDGES);
    scan_block<<<SB, 256, 0, stream>>>(counts, partial, block_sums, N_NODES);
    finalize_rowptr<<<SB, 256, 0, stream>>>(partial, block_sums, row_ptr, N_NODES, SB);
    fill_csr<<<EB, 256, 0, stream>>>(e_src, e_dst, edge_w, row_ptr, cursor, csr_pack, N_EDGES);

    const int AGGB = (N_NODES * 64 + 255) / 256;
    const int GB = (N_NODES + 63) / 64;

    aggregate<64><<<AGGB, 256, 0, stream>>>(x, row_ptr, csr_pack, AGG, N_NODES);
    gemm_dual<64, true><<<GB, 256, 0, stream>>>(AGG, W_rel0, x, W_root0, b_rel0, B1, N_NODES);
    gemm_dual<128, true><<<GB, 256, 0, stream>>>(B1, W_ro0, nullptr, nullptr, b_ro0, B2, N_NODES);
    aggregate<128><<<AGGB, 256, 0, stream>>>(B2, row_ptr, csr_pack, AGG, N_NODES);
    gemm_dual<128, true><<<GB, 256, 0, stream>>>(AGG, W_rel1, B2, W_root1, b_rel1, B1, N_NODES);
    gemm_dual<128, true><<<GB, 256, 0, stream>>>(B1, W_ro1, nullptr, nullptr, b_ro1, B2, N_NODES);
    predict<<<AGGB, 256, 0, stream>>>(B2, W_prd, b_prd, out, N_NODES);
}